// Round 8
// baseline (139.197 us; speedup 1.0000x reference)
//
#include <hip/hip_runtime.h>
#include <hip/hip_bf16.h>

// NodeAggregator forward, round 8: role-split block fusion.
// STE => forward output == degree-normalized pooled; top-k dead.
// prepW (48 blk) -> K1 {assign ∥ x-transpose} (2560 blk, 53.5KB smem union)
//   -> K2 {gemm_adj (r5-proven) ∥ gemm_feat (r7 3-buf)} (1024 blk, 72KB smem union)
//   -> gemm_pool (3-buf) -> rowsum -> finalize.
// adj body reverted to round-5 staged-B counted-vmcnt (B-direct-to-reg proven 2x slower).

typedef float f32x4 __attribute__((ext_vector_type(4)));
typedef __bf16 bf16x8 __attribute__((ext_vector_type(8)));

#define VMCNT(n) asm volatile("s_waitcnt vmcnt(" #n ")" ::: "memory")
#define LGKM0    asm volatile("s_waitcnt lgkmcnt(0)" ::: "memory")
#define SCHEDB   __builtin_amdgcn_sched_barrier(0)
#define BARRIER                                        \
  do {                                                 \
    LGKM0;                                             \
    __builtin_amdgcn_s_barrier();                      \
    asm volatile("" ::: "memory");                     \
    SCHEDB;                                            \
  } while (0)

__device__ __forceinline__ void async_load16(const void* g, void* l) {
  __builtin_amdgcn_global_load_lds((const __attribute__((address_space(1))) void*)g,
                                   (__attribute__((address_space(3))) void*)l, 16, 0, 0);
}
__device__ __forceinline__ unsigned short f2bf(float f) {
  return __builtin_bit_cast(unsigned short, (__bf16)f);
}
__device__ __forceinline__ ushort4 f4_to_bf4(float4 v) {
  ushort4 u; u.x = f2bf(v.x); u.y = f2bf(v.y); u.z = f2bf(v.z); u.w = f2bf(v.w); return u;
}

// T2 swizzle on the SOURCE granule (rule #21); LDS stays linear for gloadlds.
template <int ROWS, int BK, int NT>
__device__ __forceinline__ void stage_bf16(const __bf16* __restrict__ src, long long ld,
                                           __bf16* lds, int t) {
  constexpr int GR = BK / 8;
  constexpr int N = ROWS * GR / NT;
  static_assert(N >= 1, "stage too small");
#pragma unroll
  for (int c = 0; c < N; ++c) {
    const int idx = c * NT + t;
    const int row = idx / GR;
    const int g = idx % GR;
    const int gs = g ^ (row & (GR - 1) & 7);
    async_load16(src + (long long)row * ld + gs * 8, lds + idx * 8);
  }
}
template <int BK>
__device__ __forceinline__ bf16x8 frag(const __bf16* lds, int row, int kq) {
  constexpr int GR = BK / 8;
  const int g = kq ^ (row & (GR - 1) & 7);
  return *(const bf16x8*)(lds + row * BK + g * 8);
}

// ---------------- prepW: W1T, W2T (48 blocks; separate launch: assign depends) -----
__global__ __launch_bounds__(256) void prepW_k(const float* __restrict__ W1,
                                               const float* __restrict__ W2,
                                               __bf16* __restrict__ W1T,
                                               __bf16* __restrict__ W2T) {
  __shared__ float tile[64][65];
  const int tr = threadIdx.x >> 6, tc = threadIdx.x & 63;
  int w = blockIdx.x;
  const float* in; __bf16* out; int r0, c0, R, C;
  if (w < 32) { in = W1; out = W1T; r0 = (w >> 2) * 64; c0 = (w & 3) * 64; R = 512; C = 256; }
  else { w -= 32; in = W2; out = W2T; r0 = (w >> 2) * 64; c0 = (w & 3) * 64; R = 256; C = 256; }
#pragma unroll
  for (int i = 0; i < 16; ++i)
    tile[tr + i * 4][tc] = in[(long long)(r0 + tr + i * 4) * C + c0 + tc];
  __syncthreads();
#pragma unroll
  for (int i = 0; i < 16; ++i)
    out[(long long)(c0 + tr + i * 4) * R + r0 + tc] = (__bf16)tile[tc][tr + i * 4];
}

// ---------------- K1: assign (role 0, 512) ∥ x-transpose (roles 1-4, 2048) ---------
__device__ __forceinline__ void asg_compute(const __bf16* __restrict__ Abuf,
                                            const __bf16* __restrict__ Bbuf,
                                            f32x4 (&acc)[2][4], int wn, int l15, int l4) {
  bf16x8 af[2], bf[4];
#pragma unroll
  for (int i = 0; i < 2; ++i) af[i] = frag<32>(Abuf, i * 16 + l15, l4);
#pragma unroll
  for (int j = 0; j < 4; ++j) bf[j] = frag<32>(Bbuf, wn + j * 16 + l15, l4);
  __builtin_amdgcn_s_setprio(1);
#pragma unroll
  for (int i = 0; i < 2; ++i)
#pragma unroll
    for (int j = 0; j < 4; ++j)
      acc[i][j] = __builtin_amdgcn_mfma_f32_16x16x32_bf16(af[i], bf[j], acc[i][j], 0, 0, 0);
  __builtin_amdgcn_s_setprio(0);
}

__global__ __launch_bounds__(256) void k1_assign_prepx(
    const float* __restrict__ x, const __bf16* __restrict__ W1T,
    const __bf16* __restrict__ W2T, const float* __restrict__ b1,
    const float* __restrict__ b2, const float* __restrict__ mask,
    __bf16* __restrict__ ST, __bf16* __restrict__ xbT) {
  __shared__ __align__(16) char smem[54784];
  const int id = blockIdx.x;
  const int t = threadIdx.x;

  if (id % 5 != 0) {  // ---- x-transpose: p in [0,2048) ----
    const int p = id - id / 5 - 1;
    float* tile = (float*)smem;  // [64][65]
    const int tr = t >> 6, tc = t & 63;
    const int fb = p >> 8, rest = p & 255;
    const int nb = rest >> 3, b = rest & 7;
    const float* in = x + (long long)b * 1048576;
    __bf16* out = xbT + (long long)b * 1048576;
    const int r0 = nb * 64, c0 = fb * 64;
#pragma unroll
    for (int i = 0; i < 16; ++i)
      tile[(tr + i * 4) * 65 + tc] = in[(long long)(r0 + tr + i * 4) * 512 + c0 + tc];
    __syncthreads();
#pragma unroll
    for (int i = 0; i < 16; ++i)
      out[(long long)(c0 + tr + i * 4) * 2048 + r0 + tc] = (__bf16)tile[tc * 65 + tr + i * 4];
    return;
  }

  // ---- assign: a in [0,512) ----
  const int a = id / 5;
  __bf16* Ax0 = (__bf16*)smem;                    // 32*32
  __bf16* Ax1 = (__bf16*)(smem + 2048);
  __bf16* Bw0 = (__bf16*)(smem + 4096);           // 256*32
  __bf16* Bw1 = (__bf16*)(smem + 20480);
  __bf16* hl  = (__bf16*)(smem + 36864);          // 32*264
  float*  red = (float*)(smem + 53760);           // [2][4][32]

  const int lane = t & 63, wave = t >> 6;
  const int l15 = lane & 15, l4 = lane >> 4;
  const int wn = wave * 64;
  const long long row0 = (long long)a * 32;
  const float* Xb = x + row0 * 512;

  const int arow = t >> 3, afq = t & 7;
  const int ag = afq >> 1;
  const int aoff = arow * 32 + ((ag ^ (arow & 3)) * 8) + (afq & 1) * 4;

  auto ldx = [&](int tile) -> float4 {
    return *(const float4*)(Xb + (long long)arow * 512 + tile * 32 + afq * 4);
  };
  auto sta = [&](__bf16* dst, float4 v) { *(ushort4*)&dst[aoff] = f4_to_bf4(v); };

  f32x4 acc[2][4] = {};

  float4 xA = ldx(0);
  SCHEDB;
  stage_bf16<256, 32, 256>(W1T, 512, Bw0, t);
  SCHEDB;
  VMCNT(4); SCHEDB;
  sta(Ax0, xA);
  float4 xB = ldx(1);
  SCHEDB;
  VMCNT(1); SCHEDB;
  BARRIER;

#pragma unroll 1
  for (int tt = 0; tt < 14; tt += 2) {
    stage_bf16<256, 32, 256>(W1T + (tt + 1) * 32, 512, Bw1, t);
    SCHEDB;
    xA = ldx(tt + 2);
    SCHEDB;
    asg_compute(Ax0, Bw0, acc, wn, l15, l4);
    VMCNT(5); SCHEDB;
    sta(Ax1, xB);
    VMCNT(1); SCHEDB;
    BARRIER;
    stage_bf16<256, 32, 256>(W1T + (tt + 2) * 32, 512, Bw0, t);
    SCHEDB;
    xB = ldx(tt + 3);
    SCHEDB;
    asg_compute(Ax1, Bw1, acc, wn, l15, l4);
    VMCNT(5); SCHEDB;
    sta(Ax0, xA);
    VMCNT(1); SCHEDB;
    BARRIER;
  }
  stage_bf16<256, 32, 256>(W1T + 15 * 32, 512, Bw1, t);
  SCHEDB;
  asg_compute(Ax0, Bw0, acc, wn, l15, l4);
  VMCNT(4); SCHEDB;
  sta(Ax1, xB);
  VMCNT(0); SCHEDB;
  BARRIER;
  asg_compute(Ax1, Bw1, acc, wn, l15, l4);

  stage_bf16<256, 32, 256>(W2T, 256, Bw0, t);
  SCHEDB;
#pragma unroll
  for (int j = 0; j < 4; ++j) {
    const int col = wn + j * 16 + l15;
    const float bv = b1[col];
#pragma unroll
    for (int i = 0; i < 2; ++i)
#pragma unroll
      for (int r = 0; r < 4; ++r)
        hl[(i * 16 + l4 * 4 + r) * 264 + col] = (__bf16)fmaxf(acc[i][j][r] + bv, 0.f);
  }
  VMCNT(0); SCHEDB;
  BARRIER;

  f32x4 acc2[2][4] = {};
#pragma unroll 1
  for (int tt = 0; tt < 8; ++tt) {
    if (tt < 7) stage_bf16<256, 32, 256>(W2T + (tt + 1) * 32, 256, (tt & 1) ? Bw0 : Bw1, t);
    SCHEDB;
    const __bf16* Bc = (tt & 1) ? Bw1 : Bw0;
    bf16x8 af[2], bf[4];
#pragma unroll
    for (int i = 0; i < 2; ++i)
      af[i] = *(const bf16x8*)(&hl[(i * 16 + l15) * 264 + tt * 32 + l4 * 8]);
#pragma unroll
    for (int j = 0; j < 4; ++j) bf[j] = frag<32>(Bc, wn + j * 16 + l15, l4);
#pragma unroll
    for (int i = 0; i < 2; ++i)
#pragma unroll
      for (int j = 0; j < 4; ++j)
        acc2[i][j] = __builtin_amdgcn_mfma_f32_16x16x32_bf16(af[i], bf[j], acc2[i][j], 0, 0, 0);
    VMCNT(0); SCHEDB;
    BARRIER;
  }

  float mb[2][4], mx[2][4], sm[2][4];
#pragma unroll
  for (int i = 0; i < 2; ++i)
#pragma unroll
    for (int r = 0; r < 4; ++r) {
      mb[i][r] = -1e9f * (1.0f - mask[row0 + i * 16 + l4 * 4 + r]);
      mx[i][r] = -3.4e38f;
      sm[i][r] = 0.f;
    }
#pragma unroll
  for (int j = 0; j < 4; ++j) {
    const float bv = b2[wn + j * 16 + l15];
#pragma unroll
    for (int i = 0; i < 2; ++i)
#pragma unroll
      for (int r = 0; r < 4; ++r) {
        const float v = acc2[i][j][r] + bv + mb[i][r];
        acc2[i][j][r] = v;
        mx[i][r] = fmaxf(mx[i][r], v);
      }
  }
#pragma unroll
  for (int i = 0; i < 2; ++i)
#pragma unroll
    for (int r = 0; r < 4; ++r) {
      float m = mx[i][r];
      m = fmaxf(m, __shfl_xor(m, 1, 64)); m = fmaxf(m, __shfl_xor(m, 2, 64));
      m = fmaxf(m, __shfl_xor(m, 4, 64)); m = fmaxf(m, __shfl_xor(m, 8, 64));
      mx[i][r] = m;
    }
  if (l15 == 0)
#pragma unroll
    for (int i = 0; i < 2; ++i)
#pragma unroll
      for (int r = 0; r < 4; ++r) red[0 * 128 + wave * 32 + i * 16 + l4 * 4 + r] = mx[i][r];
  __syncthreads();
#pragma unroll
  for (int i = 0; i < 2; ++i)
#pragma unroll
    for (int r = 0; r < 4; ++r) {
      const int rl = i * 16 + l4 * 4 + r;
      mx[i][r] = fmaxf(fmaxf(red[rl], red[32 + rl]), fmaxf(red[64 + rl], red[96 + rl]));
    }
#pragma unroll
  for (int j = 0; j < 4; ++j)
#pragma unroll
    for (int i = 0; i < 2; ++i)
#pragma unroll
      for (int r = 0; r < 4; ++r) {
        const float e = __expf(acc2[i][j][r] - mx[i][r]);
        acc2[i][j][r] = e;
        sm[i][r] += e;
      }
#pragma unroll
  for (int i = 0; i < 2; ++i)
#pragma unroll
    for (int r = 0; r < 4; ++r) {
      float s = sm[i][r];
      s += __shfl_xor(s, 1, 64); s += __shfl_xor(s, 2, 64);
      s += __shfl_xor(s, 4, 64); s += __shfl_xor(s, 8, 64);
      sm[i][r] = s;
    }
  if (l15 == 0)
#pragma unroll
    for (int i = 0; i < 2; ++i)
#pragma unroll
      for (int r = 0; r < 4; ++r) red[128 + wave * 32 + i * 16 + l4 * 4 + r] = sm[i][r];
  __syncthreads();
  float inv[2][4];
#pragma unroll
  for (int i = 0; i < 2; ++i)
#pragma unroll
    for (int r = 0; r < 4; ++r) {
      const int rl = 128 + i * 16 + l4 * 4 + r;
      inv[i][r] = 1.0f / (red[rl] + red[rl + 32] + red[rl + 64] + red[rl + 96]);
    }
  const long long bb = row0 >> 11;
  const long long n0 = row0 & 2047;
  __bf16* Sb = ST + bb * 524288;
#pragma unroll
  for (int j = 0; j < 4; ++j) {
    const int col = wn + j * 16 + l15;
#pragma unroll
    for (int i = 0; i < 2; ++i) {
      ushort4 u;
      u.x = f2bf(acc2[i][j][0] * inv[i][0]);
      u.y = f2bf(acc2[i][j][1] * inv[i][1]);
      u.z = f2bf(acc2[i][j][2] * inv[i][2]);
      u.w = f2bf(acc2[i][j][3] * inv[i][3]);
      *(ushort4*)(Sb + (long long)col * 2048 + n0 + i * 16 + l4 * 4) = u;
    }
  }
}

// ---------------- K2: gemm_adj (even ids, r5 body) ∥ gemm_feat (odd ids, r7 body) --
__device__ __forceinline__ void adj_compute(const __bf16* __restrict__ Abuf,
                                            const __bf16* __restrict__ Bbuf,
                                            f32x4 (&acc)[2][4],
                                            int wn, int l15, int l4) {
#pragma unroll
  for (int ks = 0; ks < 2; ++ks) {
    bf16x8 af[2], bf[4];
#pragma unroll
    for (int i = 0; i < 2; ++i) af[i] = frag<64>(Abuf, i * 16 + l15, ks * 4 + l4);
#pragma unroll
    for (int j = 0; j < 4; ++j) bf[j] = frag<64>(Bbuf, wn + j * 16 + l15, ks * 4 + l4);
    __builtin_amdgcn_s_setprio(1);
#pragma unroll
    for (int i = 0; i < 2; ++i)
#pragma unroll
      for (int j = 0; j < 4; ++j)
        acc[i][j] = __builtin_amdgcn_mfma_f32_16x16x32_bf16(af[i], bf[j], acc[i][j], 0, 0, 0);
    __builtin_amdgcn_s_setprio(0);
  }
}

__global__ __launch_bounds__(256) void k2_adj_feat(const float* __restrict__ adj,
                                                   const __bf16* __restrict__ ST,
                                                   __bf16* __restrict__ midT,
                                                   const __bf16* __restrict__ xbT,
                                                   float* __restrict__ pfeat) {
  __shared__ __align__(16) char smem[73728];
  const int t = threadIdx.x;
  const int lane = t & 63, wave = t >> 6;
  const int l15 = lane & 15, l4 = lane >> 4;

  if ((blockIdx.x & 1) == 0) {
    // ---- gemm_adj: aid in [0,512); BM=32, BN=256, BK=64; counted-vmcnt depth-2 A --
    const int aid = blockIdx.x >> 1;
    __bf16* Aa0 = (__bf16*)smem;            // 32*64
    __bf16* Aa1 = (__bf16*)(smem + 4096);
    __bf16* Bs0 = (__bf16*)(smem + 8192);   // 256*64
    __bf16* Bs1 = (__bf16*)(smem + 40960);
    const int wn = wave * 64;
    const int bz = aid & 7;
    const long long r0 = (long long)(aid >> 3) * 32;
    const float* Ab = adj + (long long)bz * 4194304 + r0 * 2048;
    const __bf16* Bb = ST + (long long)bz * 524288;

    const int arow = t >> 4, afq = t & 15;
    const int ag = afq >> 1;
    const int aoff0 = arow * 64 + ((ag ^ (arow & 7)) * 8) + (afq & 1) * 4;
    const int aoff1 = (arow + 16) * 64 + ((ag ^ ((arow + 16) & 7)) * 8) + (afq & 1) * 4;

    auto lda4 = [&](int tile, int half) -> float4 {
      return *(const float4*)(Ab + (long long)(arow + half * 16) * 2048 + tile * 64 + afq * 4);
    };
    auto sta = [&](__bf16* dst, float4 v0, float4 v1) {
      *(ushort4*)&dst[aoff0] = f4_to_bf4(v0);
      *(ushort4*)&dst[aoff1] = f4_to_bf4(v1);
    };

    f32x4 acc[2][4] = {};

    float4 aA0 = lda4(0, 0), aA1 = lda4(0, 1);
    SCHEDB;
    stage_bf16<256, 64, 256>(Bb, 2048, Bs0, t);
    SCHEDB;
    VMCNT(8); SCHEDB;
    sta(Aa0, aA0, aA1);
    float4 aB0 = lda4(1, 0), aB1 = lda4(1, 1);
    SCHEDB;
    VMCNT(2); SCHEDB;
    BARRIER;

#pragma unroll 1
    for (int tt = 0; tt < 30; tt += 2) {
      stage_bf16<256, 64, 256>(Bb + (tt + 1) * 64, 2048, Bs1, t);
      SCHEDB;
      aA0 = lda4(tt + 2, 0); aA1 = lda4(tt + 2, 1);
      SCHEDB;
      adj_compute(Aa0, Bs0, acc, wn, l15, l4);
      VMCNT(10); SCHEDB;
      sta(Aa1, aB0, aB1);
      VMCNT(2); SCHEDB;
      BARRIER;
      stage_bf16<256, 64, 256>(Bb + (tt + 2) * 64, 2048, Bs0, t);
      SCHEDB;
      aB0 = lda4(tt + 3, 0); aB1 = lda4(tt + 3, 1);
      SCHEDB;
      adj_compute(Aa1, Bs1, acc, wn, l15, l4);
      VMCNT(10); SCHEDB;
      sta(Aa0, aA0, aA1);
      VMCNT(2); SCHEDB;
      BARRIER;
    }
    stage_bf16<256, 64, 256>(Bb + 31 * 64, 2048, Bs1, t);
    SCHEDB;
    adj_compute(Aa0, Bs0, acc, wn, l15, l4);
    VMCNT(8); SCHEDB;
    sta(Aa1, aB0, aB1);
    VMCNT(0); SCHEDB;
    BARRIER;
    adj_compute(Aa1, Bs1, acc, wn, l15, l4);

    __bf16* Cb = midT + (long long)bz * 524288;
#pragma unroll
    for (int j = 0; j < 4; ++j) {
      const int l = wn + j * 16 + l15;
#pragma unroll
      for (int i = 0; i < 2; ++i) {
        ushort4 u;
        u.x = f2bf(acc[i][j][0]); u.y = f2bf(acc[i][j][1]);
        u.z = f2bf(acc[i][j][2]); u.w = f2bf(acc[i][j][3]);
        *(ushort4*)(Cb + (long long)l * 2048 + r0 + i * 16 + l4 * 4) = u;
      }
    }
    return;
  }

  // ---- gemm_feat: fid in [0,512); BM=32(k), BN=64(f), BK=64(n); 3-buf counted ----
  const int fid = blockIdx.x >> 1;
  __bf16* AsB = (__bf16*)smem;             // 3 x 32*64
  __bf16* BsB = (__bf16*)(smem + 12288);   // 3 x 64*64
  const int wn = wave * 16;
  const int b = fid & 7, j7 = fid >> 3;
  const int kblk = j7 & 7, fblk = j7 >> 3;
  const __bf16* Ab = ST + (long long)b * 524288 + (long long)kblk * 32 * 2048;
  const __bf16* Bb = xbT + (long long)b * 1048576 + (long long)fblk * 64 * 2048;

  auto stage = [&](int s, int buf) {  // 3 gloadlds/thread
    stage_bf16<32, 64, 256>(Ab + s * 64, 2048, AsB + buf * 2048, t);
    stage_bf16<64, 64, 256>(Bb + s * 64, 2048, BsB + buf * 4096, t);
  };
  auto cmp = [&](int buf, f32x4 (&acc)[2]) {
    const __bf16* Ac = AsB + buf * 2048;
    const __bf16* Bc = BsB + buf * 4096;
#pragma unroll
    for (int ks = 0; ks < 2; ++ks) {
      bf16x8 af[2], bf;
#pragma unroll
      for (int i = 0; i < 2; ++i) af[i] = frag<64>(Ac, i * 16 + l15, ks * 4 + l4);
      bf = frag<64>(Bc, wn + l15, ks * 4 + l4);
#pragma unroll
      for (int i = 0; i < 2; ++i)
        acc[i] = __builtin_amdgcn_mfma_f32_16x16x32_bf16(af[i], bf, acc[i], 0, 0, 0);
    }
  };

  f32x4 acc[2] = {};
  stage(0, 0);
  SCHEDB;
  stage(1, 1);
  SCHEDB;
  VMCNT(3); SCHEDB;
  BARRIER;

  int cur = 0, stg = 2;
#pragma unroll 1
  for (int tt = 0; tt < 30; ++tt) {
    stage(tt + 2, stg);
    SCHEDB;
    cmp(cur, acc);
    VMCNT(3); SCHEDB;
    BARRIER;
    cur = (cur == 2) ? 0 : cur + 1;
    stg = (stg == 2) ? 0 : stg + 1;
  }
  cmp(cur, acc);
  VMCNT(0); SCHEDB;
  BARRIER;
  cur = (cur == 2) ? 0 : cur + 1;
  cmp(cur, acc);

  float* out = pfeat + (long long)b * 131072;
#pragma unroll
  for (int i = 0; i < 2; ++i)
#pragma unroll
    for (int r = 0; r < 4; ++r)
      out[(long long)(kblk * 32 + i * 16 + l4 * 4 + r) * 512 + fblk * 64 + wn + l15] =
          acc[i][r];
}

// ---------------- G4: pooled = ST @ midT^T; triple-buffer counted-vmcnt ------------
__global__ __launch_bounds__(256) void gemm_pool_k(const __bf16* __restrict__ ST,
                                                   const __bf16* __restrict__ midT,
                                                   float* __restrict__ pooled) {
  __shared__ alignas(16) __bf16 As[3][32 * 64];
  __shared__ alignas(16) __bf16 Bs[3][32 * 64];
  const int t = threadIdx.x;
  const int lane = t & 63, wave = t >> 6;
  const int l15 = lane & 15, l4 = lane >> 4;
  const int wm = (wave >> 1) * 16, wn = (wave & 1) * 16;
  const int id = blockIdx.x;
  const int b = id & 7, j7 = id >> 3;
  const int kblk = j7 & 7, lblk = j7 >> 3;
  const __bf16* Ab = ST + (long long)b * 524288 + (long long)kblk * 32 * 2048;
  const __bf16* Bb = midT + (long long)b * 524288 + (long long)lblk * 32 * 2048;

  auto stage = [&](int s, int buf) {
    stage_bf16<32, 64, 256>(Ab + s * 64, 2048, (__bf16*)As + buf * 2048, t);
    stage_bf16<32, 64, 256>(Bb + s * 64, 2048, (__bf16*)Bs + buf * 2048, t);
  };
  auto cmp = [&](int buf, f32x4& acc) {
    const __bf16* Ac = (const __bf16*)As + buf * 2048;
    const __bf16* Bc = (const __bf16*)Bs + buf * 2048;
#pragma unroll
    for (int ks = 0; ks < 2; ++ks) {
      bf16x8 af = frag<64>(Ac, wm + l15, ks * 4 + l4);
      bf16x8 bf = frag<64>(Bc, wn + l15, ks * 4 + l4);
      acc = __builtin_amdgcn_mfma_f32_16x16x32_bf16(af, bf, acc, 0, 0, 0);
    }
  };

  f32x4 acc = {};
  stage(0, 0);
  SCHEDB;
  stage(1, 1);
  SCHEDB;
  VMCNT(2); SCHEDB;
  BARRIER;

  int cur = 0, stg = 2;
#pragma unroll 1
  for (int tt = 0; tt < 30; ++tt) {
    stage(tt + 2, stg);
    SCHEDB;
    cmp(cur, acc);
    VMCNT(2); SCHEDB;
    BARRIER;
    cur = (cur == 2) ? 0 : cur + 1;
    stg = (stg == 2) ? 0 : stg + 1;
  }
  cmp(cur, acc);
  VMCNT(0); SCHEDB;
  BARRIER;
  cur = (cur == 2) ? 0 : cur + 1;
  cmp(cur, acc);

  float* out = pooled + (long long)b * 65536;
#pragma unroll
  for (int r = 0; r < 4; ++r)
    out[(long long)(kblk * 32 + wm + l4 * 4 + r) * 256 + lblk * 32 + wn + l15] = acc[r];
}

// ---------------- rowsum -> dinv; finalize ----------------
__global__ __launch_bounds__(256) void rowsum_k(const float* __restrict__ pooled,
                                                float* __restrict__ dinv) {
  const int gr = blockIdx.x * 4 + (threadIdx.x >> 6);
  const int lane = threadIdx.x & 63;
  const float* p = pooled + (long long)gr * 256;
  float s = p[lane] + p[lane + 64] + p[lane + 128] + p[lane + 192];
#pragma unroll
  for (int o = 32; o > 0; o >>= 1) s += __shfl_xor(s, o, 64);
  if (lane == 0) dinv[gr] = rsqrtf(s + 1e-9f);
}

__global__ __launch_bounds__(256) void finalize_k(const float* __restrict__ pooled,
                                                  const float* __restrict__ dinv,
                                                  float* __restrict__ outAdj,
                                                  float* __restrict__ pmask) {
  const long long i = blockIdx.x * 256LL + threadIdx.x;
  const int c = (int)(i & 255);
  const int r = (int)((i >> 8) & 255);
  const int b = (int)(i >> 16);
  outAdj[i] = pooled[i] * dinv[b * 256 + r] * dinv[b * 256 + c];
  if (i < 2048) pmask[i] = 1.0f;
}

extern "C" void kernel_launch(void* const* d_in, const int* in_sizes, int n_in,
                              void* d_out, int out_size, void* d_ws, size_t ws_size,
                              hipStream_t stream) {
  (void)in_sizes; (void)n_in; (void)out_size; (void)ws_size;
  const float* x    = (const float*)d_in[0];  // [8,2048,512]
  const float* adj  = (const float*)d_in[1];  // [8,2048,2048]
  const float* mask = (const float*)d_in[2];  // [8,2048]
  const float* W1   = (const float*)d_in[3];  // [512,256]
  const float* b1   = (const float*)d_in[4];  // [256]
  const float* W2   = (const float*)d_in[5];  // [256,256]
  const float* b2   = (const float*)d_in[6];  // [256]

  char* ws = (char*)d_ws;  // total 36,052,992 B (~34.4 MiB)
  __bf16* ST     = (__bf16*)(ws + 0);          //  8,388,608  [8][256][2048]
  __bf16* midT   = (__bf16*)(ws + 8388608);    //  8,388,608  [8][256][2048]
  __bf16* xbT    = (__bf16*)(ws + 16777216);   // 16,777,216  [8][512][2048]
  float*  pooled = (float*)(ws + 33554432);    //  2,097,152  [8][256][256]
  float*  dinv   = (float*)(ws + 35651584);    //      8,192  [8][256]
  __bf16* W1T    = (__bf16*)(ws + 35659776);   //    262,144  [256][512]
  __bf16* W2T    = (__bf16*)(ws + 35921920);   //    131,072  [256][256]

  float* pfeat  = (float*)d_out;               // [8,256,512]
  float* outAdj = (float*)d_out + 1048576;     // [8,256,256]
  float* pmask  = (float*)d_out + 1572864;     // [8,256]

  prepW_k<<<48, 256, 0, stream>>>(W1, W2, W1T, W2T);
  k1_assign_prepx<<<2560, 256, 0, stream>>>(x, W1T, W2T, b1, b2, mask, ST, xbT);
  k2_adj_feat<<<1024, 256, 0, stream>>>(adj, ST, midT, xbT, pfeat);
  gemm_pool_k<<<512, 256, 0, stream>>>(ST, midT, pooled);
  rowsum_k<<<512, 256, 0, stream>>>(pooled, dinv);
  finalize_k<<<2048, 256, 0, stream>>>(pooled, dinv, outAdj, pmask);
}

// Round 9
// 123.641 us; speedup vs baseline: 1.1258x; 1.1258x over previous
//
#include <hip/hip_runtime.h>
#include <hip/hip_bf16.h>

// NodeAggregator forward, round 9.
// STE => forward output == degree-normalized pooled; top-k dead.
// r5 structure (fusion reverted), adj rebuilt in gemm_feat's proven profile:
// 3-buffer all-gloadlds counted-vmcnt, 36KB LDS -> 4 blocks/CU, BM=32 BN=128 BK=32,
// A staged as raw f32 via gloadlds (cvt at frag-read), uniform 3 loads/thread/step.

typedef float f32x4 __attribute__((ext_vector_type(4)));
typedef __bf16 bf16x8 __attribute__((ext_vector_type(8)));

#define VMCNT(n) asm volatile("s_waitcnt vmcnt(" #n ")" ::: "memory")
#define LGKM0    asm volatile("s_waitcnt lgkmcnt(0)" ::: "memory")
#define SCHEDB   __builtin_amdgcn_sched_barrier(0)
#define BARRIER                                        \
  do {                                                 \
    LGKM0;                                             \
    __builtin_amdgcn_s_barrier();                      \
    asm volatile("" ::: "memory");                     \
    SCHEDB;                                            \
  } while (0)

__device__ __forceinline__ void async_load16(const void* g, void* l) {
  __builtin_amdgcn_global_load_lds((const __attribute__((address_space(1))) void*)g,
                                   (__attribute__((address_space(3))) void*)l, 16, 0, 0);
}
__device__ __forceinline__ unsigned short f2bf(float f) {
  return __builtin_bit_cast(unsigned short, (__bf16)f);
}
__device__ __forceinline__ ushort4 f4_to_bf4(float4 v) {
  ushort4 u; u.x = f2bf(v.x); u.y = f2bf(v.y); u.z = f2bf(v.z); u.w = f2bf(v.w); return u;
}

// T2 swizzle on the SOURCE granule (rule #21); LDS stays linear for gloadlds.
template <int ROWS, int BK, int NT>
__device__ __forceinline__ void stage_bf16(const __bf16* __restrict__ src, long long ld,
                                           __bf16* lds, int t) {
  constexpr int GR = BK / 8;
  constexpr int N = ROWS * GR / NT;
  static_assert(N >= 1, "stage too small");
#pragma unroll
  for (int c = 0; c < N; ++c) {
    const int idx = c * NT + t;
    const int row = idx / GR;
    const int g = idx % GR;
    const int gs = g ^ (row & (GR - 1) & 7);
    async_load16(src + (long long)row * ld + gs * 8, lds + idx * 8);
  }
}
template <int BK>
__device__ __forceinline__ bf16x8 frag(const __bf16* lds, int row, int kq) {
  constexpr int GR = BK / 8;
  const int g = kq ^ (row & (GR - 1) & 7);
  return *(const bf16x8*)(lds + row * BK + g * 8);
}

// ---------------- prep: x [8,2048,512] f32 -> xbT [8,512,2048] bf16; W1T; W2T ------
__global__ __launch_bounds__(256) void prep_k(const float* __restrict__ x,
                                              const float* __restrict__ W1,
                                              const float* __restrict__ W2,
                                              __bf16* __restrict__ xbT,
                                              __bf16* __restrict__ W1T,
                                              __bf16* __restrict__ W2T) {
  __shared__ float tile[64][65];
  const int tr = threadIdx.x >> 6, tc = threadIdx.x & 63;
  const int bid = blockIdx.x;
  const float* in; __bf16* out; int r0, c0, C, R;
  if (bid < 2048) {
    const int fb = bid >> 8, rest = bid & 255;
    const int nb = rest >> 3, b = rest & 7;
    in = x + (long long)b * 1048576; out = xbT + (long long)b * 1048576;
    r0 = nb * 64; c0 = fb * 64; R = 2048; C = 512;
  } else if (bid < 2080) {
    const int w = bid - 2048;
    in = W1; out = W1T; r0 = (w >> 2) * 64; c0 = (w & 3) * 64; R = 512; C = 256;
  } else {
    const int w = bid - 2080;
    in = W2; out = W2T; r0 = (w >> 2) * 64; c0 = (w & 3) * 64; R = 256; C = 256;
  }
#pragma unroll
  for (int i = 0; i < 16; ++i)
    tile[tr + i * 4][tc] = in[(long long)(r0 + tr + i * 4) * C + c0 + tc];
  __syncthreads();
#pragma unroll
  for (int i = 0; i < 16; ++i)
    out[(long long)(c0 + tr + i * 4) * R + r0 + tc] = (__bf16)tile[tc][tr + i * 4];
}

// ---------------- fused assign (unchanged, verified since r4) ----------------------
__device__ __forceinline__ void asg_compute(const __bf16* __restrict__ Abuf,
                                            const __bf16* __restrict__ Bbuf,
                                            f32x4 (&acc)[2][4], int wn, int l15, int l4) {
  bf16x8 af[2], bf[4];
#pragma unroll
  for (int i = 0; i < 2; ++i) af[i] = frag<32>(Abuf, i * 16 + l15, l4);
#pragma unroll
  for (int j = 0; j < 4; ++j) bf[j] = frag<32>(Bbuf, wn + j * 16 + l15, l4);
  __builtin_amdgcn_s_setprio(1);
#pragma unroll
  for (int i = 0; i < 2; ++i)
#pragma unroll
    for (int j = 0; j < 4; ++j)
      acc[i][j] = __builtin_amdgcn_mfma_f32_16x16x32_bf16(af[i], bf[j], acc[i][j], 0, 0, 0);
  __builtin_amdgcn_s_setprio(0);
}

__global__ __launch_bounds__(256) void assign_fused_k(
    const float* __restrict__ x, const __bf16* __restrict__ W1T,
    const __bf16* __restrict__ W2T, const float* __restrict__ b1,
    const float* __restrict__ b2, const float* __restrict__ mask,
    __bf16* __restrict__ ST) {
  __shared__ alignas(16) __bf16 Ax[2][32 * 32];
  __shared__ alignas(16) __bf16 Bw[2][256 * 32];
  __shared__ alignas(16) __bf16 hl[32 * 264];
  __shared__ float red[2][4][32];

  const int t = threadIdx.x;
  const int lane = t & 63, wave = t >> 6;
  const int l15 = lane & 15, l4 = lane >> 4;
  const int wn = wave * 64;
  const long long row0 = (long long)blockIdx.x * 32;
  const float* Xb = x + row0 * 512;

  const int arow = t >> 3, afq = t & 7;
  const int ag = afq >> 1;
  const int aoff = arow * 32 + ((ag ^ (arow & 3)) * 8) + (afq & 1) * 4;

  auto ldx = [&](int tile) -> float4 {
    return *(const float4*)(Xb + (long long)arow * 512 + tile * 32 + afq * 4);
  };
  auto sta = [&](__bf16* dst, float4 v) { *(ushort4*)&dst[aoff] = f4_to_bf4(v); };

  f32x4 acc[2][4] = {};

  float4 xA = ldx(0);
  SCHEDB;
  stage_bf16<256, 32, 256>(W1T, 512, Bw[0], t);
  SCHEDB;
  VMCNT(4); SCHEDB;
  sta(Ax[0], xA);
  float4 xB = ldx(1);
  SCHEDB;
  VMCNT(1); SCHEDB;
  BARRIER;

#pragma unroll 1
  for (int tt = 0; tt < 14; tt += 2) {
    stage_bf16<256, 32, 256>(W1T + (tt + 1) * 32, 512, Bw[1], t);
    SCHEDB;
    xA = ldx(tt + 2);
    SCHEDB;
    asg_compute(Ax[0], Bw[0], acc, wn, l15, l4);
    VMCNT(5); SCHEDB;
    sta(Ax[1], xB);
    VMCNT(1); SCHEDB;
    BARRIER;
    stage_bf16<256, 32, 256>(W1T + (tt + 2) * 32, 512, Bw[0], t);
    SCHEDB;
    xB = ldx(tt + 3);
    SCHEDB;
    asg_compute(Ax[1], Bw[1], acc, wn, l15, l4);
    VMCNT(5); SCHEDB;
    sta(Ax[0], xA);
    VMCNT(1); SCHEDB;
    BARRIER;
  }
  stage_bf16<256, 32, 256>(W1T + 15 * 32, 512, Bw[1], t);
  SCHEDB;
  asg_compute(Ax[0], Bw[0], acc, wn, l15, l4);
  VMCNT(4); SCHEDB;
  sta(Ax[1], xB);
  VMCNT(0); SCHEDB;
  BARRIER;
  asg_compute(Ax[1], Bw[1], acc, wn, l15, l4);

  stage_bf16<256, 32, 256>(W2T, 256, Bw[0], t);
  SCHEDB;
#pragma unroll
  for (int j = 0; j < 4; ++j) {
    const int col = wn + j * 16 + l15;
    const float bv = b1[col];
#pragma unroll
    for (int i = 0; i < 2; ++i)
#pragma unroll
      for (int r = 0; r < 4; ++r)
        hl[(i * 16 + l4 * 4 + r) * 264 + col] = (__bf16)fmaxf(acc[i][j][r] + bv, 0.f);
  }
  VMCNT(0); SCHEDB;
  BARRIER;

  f32x4 acc2[2][4] = {};
#pragma unroll 1
  for (int tt = 0; tt < 8; ++tt) {
    if (tt < 7) stage_bf16<256, 32, 256>(W2T + (tt + 1) * 32, 256, Bw[(tt & 1) ^ 1], t);
    SCHEDB;
    const __bf16* Bc = Bw[tt & 1];
    bf16x8 af[2], bf[4];
#pragma unroll
    for (int i = 0; i < 2; ++i)
      af[i] = *(const bf16x8*)(&hl[(i * 16 + l15) * 264 + tt * 32 + l4 * 8]);
#pragma unroll
    for (int j = 0; j < 4; ++j) bf[j] = frag<32>(Bc, wn + j * 16 + l15, l4);
#pragma unroll
    for (int i = 0; i < 2; ++i)
#pragma unroll
      for (int j = 0; j < 4; ++j)
        acc2[i][j] = __builtin_amdgcn_mfma_f32_16x16x32_bf16(af[i], bf[j], acc2[i][j], 0, 0, 0);
    VMCNT(0); SCHEDB;
    BARRIER;
  }

  float mb[2][4], mx[2][4], sm[2][4];
#pragma unroll
  for (int i = 0; i < 2; ++i)
#pragma unroll
    for (int r = 0; r < 4; ++r) {
      mb[i][r] = -1e9f * (1.0f - mask[row0 + i * 16 + l4 * 4 + r]);
      mx[i][r] = -3.4e38f;
      sm[i][r] = 0.f;
    }
#pragma unroll
  for (int j = 0; j < 4; ++j) {
    const float bv = b2[wn + j * 16 + l15];
#pragma unroll
    for (int i = 0; i < 2; ++i)
#pragma unroll
      for (int r = 0; r < 4; ++r) {
        const float v = acc2[i][j][r] + bv + mb[i][r];
        acc2[i][j][r] = v;
        mx[i][r] = fmaxf(mx[i][r], v);
      }
  }
#pragma unroll
  for (int i = 0; i < 2; ++i)
#pragma unroll
    for (int r = 0; r < 4; ++r) {
      float m = mx[i][r];
      m = fmaxf(m, __shfl_xor(m, 1, 64)); m = fmaxf(m, __shfl_xor(m, 2, 64));
      m = fmaxf(m, __shfl_xor(m, 4, 64)); m = fmaxf(m, __shfl_xor(m, 8, 64));
      mx[i][r] = m;
    }
  if (l15 == 0)
#pragma unroll
    for (int i = 0; i < 2; ++i)
#pragma unroll
      for (int r = 0; r < 4; ++r) red[0][wave][i * 16 + l4 * 4 + r] = mx[i][r];
  __syncthreads();
#pragma unroll
  for (int i = 0; i < 2; ++i)
#pragma unroll
    for (int r = 0; r < 4; ++r) {
      const int rl = i * 16 + l4 * 4 + r;
      mx[i][r] = fmaxf(fmaxf(red[0][0][rl], red[0][1][rl]),
                       fmaxf(red[0][2][rl], red[0][3][rl]));
    }
#pragma unroll
  for (int j = 0; j < 4; ++j)
#pragma unroll
    for (int i = 0; i < 2; ++i)
#pragma unroll
      for (int r = 0; r < 4; ++r) {
        const float e = __expf(acc2[i][j][r] - mx[i][r]);
        acc2[i][j][r] = e;
        sm[i][r] += e;
      }
#pragma unroll
  for (int i = 0; i < 2; ++i)
#pragma unroll
    for (int r = 0; r < 4; ++r) {
      float s = sm[i][r];
      s += __shfl_xor(s, 1, 64); s += __shfl_xor(s, 2, 64);
      s += __shfl_xor(s, 4, 64); s += __shfl_xor(s, 8, 64);
      sm[i][r] = s;
    }
  if (l15 == 0)
#pragma unroll
    for (int i = 0; i < 2; ++i)
#pragma unroll
      for (int r = 0; r < 4; ++r) red[1][wave][i * 16 + l4 * 4 + r] = sm[i][r];
  __syncthreads();
  float inv[2][4];
#pragma unroll
  for (int i = 0; i < 2; ++i)
#pragma unroll
    for (int r = 0; r < 4; ++r) {
      const int rl = i * 16 + l4 * 4 + r;
      inv[i][r] = 1.0f / (red[1][0][rl] + red[1][1][rl] + red[1][2][rl] + red[1][3][rl]);
    }
  const long long bb = row0 >> 11;
  const long long n0 = row0 & 2047;
  __bf16* Sb = ST + bb * 524288;
#pragma unroll
  for (int j = 0; j < 4; ++j) {
    const int col = wn + j * 16 + l15;
#pragma unroll
    for (int i = 0; i < 2; ++i) {
      ushort4 u;
      u.x = f2bf(acc2[i][j][0] * inv[i][0]);
      u.y = f2bf(acc2[i][j][1] * inv[i][1]);
      u.z = f2bf(acc2[i][j][2] * inv[i][2]);
      u.w = f2bf(acc2[i][j][3] * inv[i][3]);
      *(ushort4*)(Sb + (long long)col * 2048 + n0 + i * 16 + l4 * 4) = u;
    }
  }
}

// ---------------- G3: midT = (adj @ S)^T; feat-profile rebuild ----------------------
// BM=32 (adj rows), BN=128 (cluster half), BK=32; 3-buf all-gloadlds, 36KB -> 4/CU.
// A staged as raw f32 (16B granules type-agnostic), cvt to bf16 at frag read.
__global__ __launch_bounds__(256) void gemm_adj_k(const float* __restrict__ adj,
                                                  const __bf16* __restrict__ ST,
                                                  __bf16* __restrict__ midT) {
  __shared__ alignas(16) __bf16 As[3][32 * 64];   // f32 data: 32 rows x 32 k x 4B = 4KB/buf
  __shared__ alignas(16) __bf16 Bs[3][128 * 32];  // 8KB/buf
  const int t = threadIdx.x;
  const int lane = t & 63, wave = t >> 6;
  const int l15 = lane & 15, l4 = lane >> 4;
  const int wn = wave * 32;
  const int id = blockIdx.x;   // 1024: batch=id&7 (XCD pin), nh=bit3, slab=id>>4
  const int bz = id & 7;
  const int nh = (id >> 3) & 1;
  const long long r0 = (long long)(id >> 4) * 32;
  // A viewed as bf16-units: row stride 4096, K-tile stride 64 (=32 f32)
  const __bf16* Abh = (const __bf16*)(adj + (long long)bz * 4194304 + r0 * 2048);
  const __bf16* Bb = ST + (long long)bz * 524288 + (long long)nh * 128 * 2048;

  auto stage = [&](int s, int buf) {  // 1 A-gloadlds + 2 B-gloadlds per thread
    stage_bf16<32, 64, 256>(Abh + s * 64, 4096, (__bf16*)As + buf * 2048, t);
    stage_bf16<128, 32, 256>(Bb + s * 32, 2048, (__bf16*)Bs + buf * 4096, t);
  };
  auto afrag = [&](const __bf16* Ac, int row) {
    // 8 f32 at [row][l4*8..+8] = granules l4*2, l4*2+1 (swizzle inside frag<64>)
    f32x4 lo = __builtin_bit_cast(f32x4, frag<64>(Ac, row, l4 * 2));
    f32x4 hi = __builtin_bit_cast(f32x4, frag<64>(Ac, row, l4 * 2 + 1));
    bf16x8 r;
    r[0] = (__bf16)lo[0]; r[1] = (__bf16)lo[1]; r[2] = (__bf16)lo[2]; r[3] = (__bf16)lo[3];
    r[4] = (__bf16)hi[0]; r[5] = (__bf16)hi[1]; r[6] = (__bf16)hi[2]; r[7] = (__bf16)hi[3];
    return r;
  };
  f32x4 acc[2][2] = {};
  auto cmp = [&](int buf) {
    const __bf16* Ac = (const __bf16*)As + buf * 2048;
    const __bf16* Bc = (const __bf16*)Bs + buf * 4096;
    bf16x8 af[2], bf[2];
#pragma unroll
    for (int i = 0; i < 2; ++i) af[i] = afrag(Ac, i * 16 + l15);
#pragma unroll
    for (int j = 0; j < 2; ++j) bf[j] = frag<32>(Bc, wn + j * 16 + l15, l4);
    __builtin_amdgcn_s_setprio(1);
#pragma unroll
    for (int i = 0; i < 2; ++i)
#pragma unroll
      for (int j = 0; j < 2; ++j)
        acc[i][j] = __builtin_amdgcn_mfma_f32_16x16x32_bf16(af[i], bf[j], acc[i][j], 0, 0, 0);
    __builtin_amdgcn_s_setprio(0);
  };

  stage(0, 0);
  SCHEDB;
  stage(1, 1);
  SCHEDB;
  VMCNT(3); SCHEDB;  // tile0 done; tile1 (3 loads) in flight
  BARRIER;

  int cur = 0, stg = 2;
#pragma unroll 1
  for (int tt = 0; tt < 62; ++tt) {  // K=2048, BK=32 -> 64 tiles
    stage(tt + 2, stg);
    SCHEDB;                          // [t+1:3, t+2:3]
    cmp(cur);
    VMCNT(3); SCHEDB;                // retire t+1; t+2 stays in flight
    BARRIER;
    cur = (cur == 2) ? 0 : cur + 1;
    stg = (stg == 2) ? 0 : stg + 1;
  }
  cmp(cur);                          // tile 62
  VMCNT(0); SCHEDB;                  // tile 63 done
  BARRIER;
  cur = (cur == 2) ? 0 : cur + 1;
  cmp(cur);                          // tile 63

  __bf16* Cb = midT + (long long)bz * 524288;
#pragma unroll
  for (int j = 0; j < 2; ++j) {
    const int l = nh * 128 + wn + j * 16 + l15;
#pragma unroll
    for (int i = 0; i < 2; ++i) {
      ushort4 u;
      u.x = f2bf(acc[i][j][0]); u.y = f2bf(acc[i][j][1]);
      u.z = f2bf(acc[i][j][2]); u.w = f2bf(acc[i][j][3]);
      *(ushort4*)(Cb + (long long)l * 2048 + r0 + i * 16 + l4 * 4) = u;
    }
  }
}

// ---------------- G5: pfeat = ST @ xbT^T; triple-buffer counted-vmcnt (proven) -----
__global__ __launch_bounds__(256) void gemm_feat_k(const __bf16* __restrict__ ST,
                                                   const __bf16* __restrict__ xbT,
                                                   float* __restrict__ pfeat) {
  __shared__ alignas(16) __bf16 As[3][32 * 64];  // 12 KB
  __shared__ alignas(16) __bf16 Bs[3][64 * 64];  // 24 KB
  const int t = threadIdx.x;
  const int lane = t & 63, wave = t >> 6;
  const int l15 = lane & 15, l4 = lane >> 4;
  const int wn = wave * 16;
  const int id = blockIdx.x;   // 512: b=id&7 (XCD pin), kblk, fblk
  const int b = id & 7, j7 = id >> 3;
  const int kblk = j7 & 7, fblk = j7 >> 3;
  const __bf16* Ab = ST + (long long)b * 524288 + (long long)kblk * 32 * 2048;
  const __bf16* Bb = xbT + (long long)b * 1048576 + (long long)fblk * 64 * 2048;

  auto stage = [&](int s, int buf) {  // 3 gloadlds/thread
    stage_bf16<32, 64, 256>(Ab + s * 64, 2048, (__bf16*)As + buf * 2048, t);
    stage_bf16<64, 64, 256>(Bb + s * 64, 2048, (__bf16*)Bs + buf * 4096, t);
  };
  auto cmp = [&](int buf, f32x4 (&acc)[2]) {
    const __bf16* Ac = (const __bf16*)As + buf * 2048;
    const __bf16* Bc = (const __bf16*)Bs + buf * 4096;
#pragma unroll
    for (int ks = 0; ks < 2; ++ks) {
      bf16x8 af[2], bf;
#pragma unroll
      for (int i = 0; i < 2; ++i) af[i] = frag<64>(Ac, i * 16 + l15, ks * 4 + l4);
      bf = frag<64>(Bc, wn + l15, ks * 4 + l4);
#pragma unroll
      for (int i = 0; i < 2; ++i)
        acc[i] = __builtin_amdgcn_mfma_f32_16x16x32_bf16(af[i], bf, acc[i], 0, 0, 0);
    }
  };

  f32x4 acc[2] = {};
  stage(0, 0);
  SCHEDB;
  stage(1, 1);
  SCHEDB;
  VMCNT(3); SCHEDB;
  BARRIER;

  int cur = 0, stg = 2;
#pragma unroll 1
  for (int tt = 0; tt < 30; ++tt) {
    stage(tt + 2, stg);
    SCHEDB;
    cmp(cur, acc);
    VMCNT(3); SCHEDB;
    BARRIER;
    cur = (cur == 2) ? 0 : cur + 1;
    stg = (stg == 2) ? 0 : stg + 1;
  }
  cmp(cur, acc);
  VMCNT(0); SCHEDB;
  BARRIER;
  cur = (cur == 2) ? 0 : cur + 1;
  cmp(cur, acc);

  float* out = pfeat + (long long)b * 131072;
#pragma unroll
  for (int i = 0; i < 2; ++i)
#pragma unroll
    for (int r = 0; r < 4; ++r)
      out[(long long)(kblk * 32 + i * 16 + l4 * 4 + r) * 512 + fblk * 64 + wn + l15] =
          acc[i][r];
}

// ---------------- G4: pooled = ST @ midT^T; triple-buffer counted-vmcnt (proven) ---
__global__ __launch_bounds__(256) void gemm_pool_k(const __bf16* __restrict__ ST,
                                                   const __bf16* __restrict__ midT,
                                                   float* __restrict__ pooled) {
  __shared__ alignas(16) __bf16 As[3][32 * 64];
  __shared__ alignas(16) __bf16 Bs[3][32 * 64];
  const int t = threadIdx.x;
  const int lane = t & 63, wave = t >> 6;
  const int l15 = lane & 15, l4 = lane >> 4;
  const int wm = (wave >> 1) * 16, wn = (wave & 1) * 16;
  const int id = blockIdx.x;
  const int b = id & 7, j7 = id >> 3;
  const int kblk = j7 & 7, lblk = j7 >> 3;
  const __bf16* Ab = ST + (long long)b * 524288 + (long long)kblk * 32 * 2048;
  const __bf16* Bb = midT + (long long)b * 524288 + (long long)lblk * 32 * 2048;

  auto stage = [&](int s, int buf) {
    stage_bf16<32, 64, 256>(Ab + s * 64, 2048, (__bf16*)As + buf * 2048, t);
    stage_bf16<32, 64, 256>(Bb + s * 64, 2048, (__bf16*)Bs + buf * 2048, t);
  };
  auto cmp = [&](int buf, f32x4& acc) {
    const __bf16* Ac = (const __bf16*)As + buf * 2048;
    const __bf16* Bc = (const __bf16*)Bs + buf * 2048;
#pragma unroll
    for (int ks = 0; ks < 2; ++ks) {
      bf16x8 af = frag<64>(Ac, wm + l15, ks * 4 + l4);
      bf16x8 bf = frag<64>(Bc, wn + l15, ks * 4 + l4);
      acc = __builtin_amdgcn_mfma_f32_16x16x32_bf16(af, bf, acc, 0, 0, 0);
    }
  };

  f32x4 acc = {};
  stage(0, 0);
  SCHEDB;
  stage(1, 1);
  SCHEDB;
  VMCNT(2); SCHEDB;
  BARRIER;

  int cur = 0, stg = 2;
#pragma unroll 1
  for (int tt = 0; tt < 30; ++tt) {
    stage(tt + 2, stg);
    SCHEDB;
    cmp(cur, acc);
    VMCNT(2); SCHEDB;
    BARRIER;
    cur = (cur == 2) ? 0 : cur + 1;
    stg = (stg == 2) ? 0 : stg + 1;
  }
  cmp(cur, acc);
  VMCNT(0); SCHEDB;
  BARRIER;
  cur = (cur == 2) ? 0 : cur + 1;
  cmp(cur, acc);

  float* out = pooled + (long long)b * 65536;
#pragma unroll
  for (int r = 0; r < 4; ++r)
    out[(long long)(kblk * 32 + wm + l4 * 4 + r) * 256 + lblk * 32 + wn + l15] = acc[r];
}

// ---------------- rowsum -> dinv; finalize ----------------
__global__ __launch_bounds__(256) void rowsum_k(const float* __restrict__ pooled,
                                                float* __restrict__ dinv) {
  const int gr = blockIdx.x * 4 + (threadIdx.x >> 6);
  const int lane = threadIdx.x & 63;
  const float* p = pooled + (long long)gr * 256;
  float s = p[lane] + p[lane + 64] + p[lane + 128] + p[lane + 192];
#pragma unroll
  for (int o = 32; o > 0; o >>= 1) s += __shfl_xor(s, o, 64);
  if (lane == 0) dinv[gr] = rsqrtf(s + 1e-9f);
}

__global__ __launch_bounds__(256) void finalize_k(const float* __restrict__ pooled,
                                                  const float* __restrict__ dinv,
                                                  float* __restrict__ outAdj,
                                                  float* __restrict__ pmask) {
  const long long i = blockIdx.x * 256LL + threadIdx.x;
  const int c = (int)(i & 255);
  const int r = (int)((i >> 8) & 255);
  const int b = (int)(i >> 16);
  outAdj[i] = pooled[i] * dinv[b * 256 + r] * dinv[b * 256 + c];
  if (i < 2048) pmask[i] = 1.0f;
}

extern "C" void kernel_launch(void* const* d_in, const int* in_sizes, int n_in,
                              void* d_out, int out_size, void* d_ws, size_t ws_size,
                              hipStream_t stream) {
  (void)in_sizes; (void)n_in; (void)out_size; (void)ws_size;
  const float* x    = (const float*)d_in[0];  // [8,2048,512]
  const float* adj  = (const float*)d_in[1];  // [8,2048,2048]
  const float* mask = (const float*)d_in[2];  // [8,2048]
  const float* W1   = (const float*)d_in[3];  // [512,256]
  const float* b1   = (const float*)d_in[4];  // [256]
  const float* W2   = (const float*)d_in[5];  // [256,256]
  const float* b2   = (const float*)d_in[6];  // [256]

  char* ws = (char*)d_ws;  // total 36,052,992 B (~34.4 MiB)
  __bf16* ST     = (__bf16*)(ws + 0);          //  8,388,608  [8][256][2048]
  __bf16* midT   = (__bf16*)(ws + 8388608);    //  8,388,608  [8][256][2048]
  __bf16* xbT    = (__bf16*)(ws + 16777216);   // 16,777,216  [8][512][2048]
  float*  pooled = (float*)(ws + 33554432);    //  2,097,152  [8][256][256]
  float*  dinv   = (float*)(ws + 35651584);    //      8,192  [8][256]
  __bf16* W1T    = (__bf16*)(ws + 35659776);   //    262,144  [256][512]
  __bf16* W2T    = (__bf16*)(ws + 35921920);   //    131,072  [256][256]

  float* pfeat  = (float*)d_out;               // [8,256,512]
  float* outAdj = (float*)d_out + 1048576;     // [8,256,256]
  float* pmask  = (float*)d_out + 1572864;     // [8,256]

  prep_k<<<2096, 256, 0, stream>>>(x, W1, W2, xbT, W1T, W2T);
  assign_fused_k<<<512, 256, 0, stream>>>(x, W1T, W2T, b1, b2, mask, ST);
  gemm_feat_k<<<512, 256, 0, stream>>>(ST, xbT, pfeat);
  gemm_adj_k<<<1024, 256, 0, stream>>>(adj, ST, midT);
  gemm_pool_k<<<512, 256, 0, stream>>>(ST, midT, pooled);
  rowsum_k<<<512, 256, 0, stream>>>(pooled, dinv);
  finalize_k<<<2048, 256, 0, stream>>>(pooled, dinv, outAdj, pmask);
}